// Round 17
// baseline (881.274 us; speedup 1.0000x reference)
//
#include <hip/hip_runtime.h>

typedef unsigned short u16;
typedef short s16;
typedef s16 s16x8 __attribute__((ext_vector_type(8)));
typedef float f32x4 __attribute__((ext_vector_type(4)));

__device__ __forceinline__ float bf2f(u16 u){
  union { unsigned int i; float f; } v; v.i = ((unsigned int)u) << 16; return v.f;
}
__device__ __forceinline__ u16 f2bf(float f){
  union { float f; unsigned int u; } v; v.f = f;
  unsigned int r = (v.u + 0x7fffu + ((v.u >> 16) & 1u)) >> 16;
  return (u16)r;
}
__device__ __forceinline__ float gelu_f(float x){
  return 0.5f * x * (1.f + erff(x * 0.70710678118654752440f));
}
__device__ __forceinline__ float ldw(const void* p, long i, int fl){
  return fl ? bf2f(((const u16*)p)[i]) : ((const float*)p)[i];
}
__device__ __forceinline__ float4 ldw4(const void* p, long i, int fl){
  if (fl){
    ushort4 w = *(const ushort4*)((const u16*)p + i);
    return make_float4(bf2f(w.x), bf2f(w.y), bf2f(w.z), bf2f(w.w));
  }
  return *(const float4*)((const float*)p + i);
}

// ---------------- dtype sniffer (flag[0]=dtype, flag[1]=0 const) --------
__global__ __launch_bounds__(256) void k_sniff(const unsigned int* __restrict__ w,
                                               int n, int* __restrict__ flag){
  __shared__ int cnt[256];
  int c = 0;
  for (int i = threadIdx.x; i < n; i += 256){
    unsigned e = (w[i] >> 7) & 0xFFu;
    c += (e >= 120u && e <= 127u) ? 1 : 0;
  }
  cnt[threadIdx.x] = c; __syncthreads();
  for (int s = 128; s > 0; s >>= 1){
    if (threadIdx.x < s) cnt[threadIdx.x] += cnt[threadIdx.x + s];
    __syncthreads();
  }
  if (threadIdx.x == 0) flag[0] = (2 * cnt[0] > n) ? 1 : 0;
  if (threadIdx.x == 1) flag[1] = 0;
}

// ---- zero-pad xproj (48x256 -> 64x256) / dt_w (256x16 -> 256x64) / dt_b ----
__global__ __launch_bounds__(256) void k_pad(
  const void* __restrict__ wx, const void* __restrict__ wd,
  const void* __restrict__ bd,
  float* __restrict__ px, float* __restrict__ pd, float* __restrict__ pb,
  const int* __restrict__ flagp)
{
  int fl = *flagp;
  int i = blockIdx.x * 256 + threadIdx.x;
  if (i < 16384){
    int r = i >> 8, c = i & 255;
    px[i] = (r < 48) ? ldw(wx, r*256 + c, fl) : 0.f;
  } else if (i < 32768){
    int j = i - 16384;
    int n = j >> 6, k = j & 63;
    pd[j] = (k < 16) ? ldw(wd, n*16 + k, fl) : 0.f;
  } else if (i < 33024){
    pb[i - 32768] = ldw(bd, i - 32768, fl);
  }
}

// ---------------- MFMA GEMM ----------------
// Flag indices select dtype per stream: flagp[idx] (0=input dtype, 1=fp32).
// outmode: 0 fp32, 2 dynamic, 3 bf16, 4 softplus(dt+2*bias) -> Cf, *xc -> C2.
__global__ __launch_bounds__(256) void k_gemm_mfma(
  const void* __restrict__ A, int aflidx, int lda, int K, int N,
  const void* __restrict__ W, const void* __restrict__ W2, int nsplit, int wflidx,
  const void* __restrict__ bias,
  float* __restrict__ Cf, u16* __restrict__ Cb, int ldc,
  float* __restrict__ C2, int ldc2,
  const void* __restrict__ resid, int rflidx, int ldr,
  const void* __restrict__ csrc, int cflidx, float* __restrict__ cdst,
  float oscale, int act_gelu, int outmode, const int* __restrict__ flagp)
{
  const int fl  = flagp[0];
  const int afl = flagp[aflidx];
  const int wfl = flagp[wflidx];
  const int rfl = flagp[rflidx];
  const int cfl = flagp[cflidx];
  __shared__ u16 As[64*72];
  __shared__ u16 Bs[64*72];
  const int tid = threadIdx.x;
  const int w = tid >> 6, lane = tid & 63, quad = lane >> 4, m = lane & 15;
  const int m0 = blockIdx.y << 6, n0 = blockIdx.x << 6;
  const int srow = tid >> 2, sc0 = (tid & 3) << 4;
  const int reg2 = (n0 >= nsplit);
  const void* Wp = reg2 ? W2 : W;
  const int nbase = reg2 ? nsplit : 0;

  f32x4 acc[4];
  #pragma unroll
  for (int ct = 0; ct < 4; ++ct) acc[ct] = (f32x4){0.f,0.f,0.f,0.f};

  for (int k0 = 0; k0 < K; k0 += 64){
    {
      long ab = (long)(m0 + srow) * lda + k0 + sc0;
      #pragma unroll
      for (int g = 0; g < 2; ++g){
        float4 a0 = ldw4(A, ab + g*8, afl);
        float4 a1 = ldw4(A, ab + g*8 + 4, afl);
        if (act_gelu){
          a0.x=gelu_f(a0.x); a0.y=gelu_f(a0.y); a0.z=gelu_f(a0.z); a0.w=gelu_f(a0.w);
          a1.x=gelu_f(a1.x); a1.y=gelu_f(a1.y); a1.z=gelu_f(a1.z); a1.w=gelu_f(a1.w);
        }
        union { u16 h[8]; uint4 v; } pk;
        pk.h[0]=f2bf(a0.x); pk.h[1]=f2bf(a0.y); pk.h[2]=f2bf(a0.z); pk.h[3]=f2bf(a0.w);
        pk.h[4]=f2bf(a1.x); pk.h[5]=f2bf(a1.y); pk.h[6]=f2bf(a1.z); pk.h[7]=f2bf(a1.w);
        *(uint4*)&As[srow*72 + sc0 + g*8] = pk.v;
      }
    }
    {
      long wb = (long)(n0 + srow - nbase) * K + k0 + sc0;
      #pragma unroll
      for (int g = 0; g < 2; ++g){
        float4 b0 = ldw4(Wp, wb + g*8, wfl);
        float4 b1 = ldw4(Wp, wb + g*8 + 4, wfl);
        union { u16 h[8]; uint4 v; } pk;
        pk.h[0]=f2bf(b0.x); pk.h[1]=f2bf(b0.y); pk.h[2]=f2bf(b0.z); pk.h[3]=f2bf(b0.w);
        pk.h[4]=f2bf(b1.x); pk.h[5]=f2bf(b1.y); pk.h[6]=f2bf(b1.z); pk.h[7]=f2bf(b1.w);
        *(uint4*)&Bs[srow*72 + sc0 + g*8] = pk.v;
      }
    }
    __syncthreads();

    s16x8 av[2];
    #pragma unroll
    for (int s = 0; s < 2; ++s)
      av[s] = *(const s16x8*)&As[(w*16 + m)*72 + s*32 + quad*8];
    #pragma unroll
    for (int ct = 0; ct < 4; ++ct)
      #pragma unroll
      for (int s = 0; s < 2; ++s){
        s16x8 bv = *(const s16x8*)&Bs[(ct*16 + m)*72 + s*32 + quad*8];
        acc[ct] = __builtin_amdgcn_mfma_f32_16x16x32_bf16(av[s], bv, acc[ct], 0, 0, 0);
      }
    __syncthreads();
  }

  #pragma unroll
  for (int r = 0; r < 4; ++r){
    int gm = m0 + w*16 + quad*4 + r;
    #pragma unroll
    for (int ct = 0; ct < 4; ++ct){
      int gn = n0 + ct*16 + m;
      float v = acc[ct][r];
      if (reg2){
        C2[(long)gm * ldc2 + (gn - nsplit)] = v;
      } else if (outmode == 4){
        float bv = ldw(bias, gn, wfl);
        float dl = v + bv + bv;              // dt + 2*dt_bias (ref's double add)
        float delta = (dl > 20.f) ? dl : __logf(1.f + __expf(dl));
        Cf[(long)gm * ldc + gn] = delta;
        C2[(long)gm * ldc2 + gn] = delta * ldw(resid, (long)gm * ldr + gn, rfl);
      } else {
        if (bias) v += ldw(bias, gn, wfl);
        v *= oscale;
        if (resid) v += ldw(resid, (long)gm * ldr + gn, rfl);
        long off = (long)gm * ldc + gn;
        if (outmode == 2){
          if (fl) Cb[off] = f2bf(v); else Cf[off] = v;
        } else if (outmode == 3){
          Cb[off] = f2bf(v);
        } else {
          Cf[off] = v;
        }
        if (cdst) cdst[(long)gm * ldc + gn] = ldw(csrc, (long)gm * 256 + gn, cfl);
      }
    }
  }
}

// ---------------- z-batched MFMA GEMM (up to 4 independent problems) ----------------
struct GB4 {
  const float* A[4]; const void* W[4]; const void* bias[4];
  float* Cf[4]; u16* Cb[4]; const float* resid[4];
  const void* csrc[4]; float* cdst[4]; float osc[4]; int cfl[4];
};

__global__ __launch_bounds__(256) void k_gemmb(
  GB4 gb, int lda, int K, int N, int ldc, int ldr,
  int act_gelu, int outmode, const int* __restrict__ flagp)
{
  const int fl = flagp[0];
  const int z = blockIdx.z;
  const float* A = gb.A[z]; const void* W = gb.W[z]; const void* bias = gb.bias[z];
  float* Cf = gb.Cf[z]; u16* Cb = gb.Cb[z]; const float* resid = gb.resid[z];
  const void* csrc = gb.csrc[z]; float* cdst = gb.cdst[z];
  const float osc = gb.osc[z];
  const int cfl = flagp[gb.cfl[z]];

  __shared__ u16 As[64*72];
  __shared__ u16 Bs[64*72];
  const int tid = threadIdx.x;
  const int w = tid >> 6, lane = tid & 63, quad = lane >> 4, m = lane & 15;
  const int m0 = blockIdx.y << 6, n0 = blockIdx.x << 6;
  const int srow = tid >> 2, sc0 = (tid & 3) << 4;

  f32x4 acc[4];
  #pragma unroll
  for (int ct = 0; ct < 4; ++ct) acc[ct] = (f32x4){0.f,0.f,0.f,0.f};

  for (int k0 = 0; k0 < K; k0 += 64){
    {
      const float* ar = A + (long)(m0 + srow) * lda + k0 + sc0;
      #pragma unroll
      for (int g = 0; g < 2; ++g){
        float4 a0 = *(const float4*)(ar + g*8);
        float4 a1 = *(const float4*)(ar + g*8 + 4);
        if (act_gelu){
          a0.x=gelu_f(a0.x); a0.y=gelu_f(a0.y); a0.z=gelu_f(a0.z); a0.w=gelu_f(a0.w);
          a1.x=gelu_f(a1.x); a1.y=gelu_f(a1.y); a1.z=gelu_f(a1.z); a1.w=gelu_f(a1.w);
        }
        union { u16 h[8]; uint4 v; } pk;
        pk.h[0]=f2bf(a0.x); pk.h[1]=f2bf(a0.y); pk.h[2]=f2bf(a0.z); pk.h[3]=f2bf(a0.w);
        pk.h[4]=f2bf(a1.x); pk.h[5]=f2bf(a1.y); pk.h[6]=f2bf(a1.z); pk.h[7]=f2bf(a1.w);
        *(uint4*)&As[srow*72 + sc0 + g*8] = pk.v;
      }
    }
    {
      long wb = (long)(n0 + srow) * K + k0 + sc0;
      #pragma unroll
      for (int g = 0; g < 2; ++g){
        float4 b0 = ldw4(W, wb + g*8, fl);
        float4 b1 = ldw4(W, wb + g*8 + 4, fl);
        union { u16 h[8]; uint4 v; } pk;
        pk.h[0]=f2bf(b0.x); pk.h[1]=f2bf(b0.y); pk.h[2]=f2bf(b0.z); pk.h[3]=f2bf(b0.w);
        pk.h[4]=f2bf(b1.x); pk.h[5]=f2bf(b1.y); pk.h[6]=f2bf(b1.z); pk.h[7]=f2bf(b1.w);
        *(uint4*)&Bs[srow*72 + sc0 + g*8] = pk.v;
      }
    }
    __syncthreads();

    s16x8 av[2];
    #pragma unroll
    for (int s = 0; s < 2; ++s)
      av[s] = *(const s16x8*)&As[(w*16 + m)*72 + s*32 + quad*8];
    #pragma unroll
    for (int ct = 0; ct < 4; ++ct)
      #pragma unroll
      for (int s = 0; s < 2; ++s){
        s16x8 bv = *(const s16x8*)&Bs[(ct*16 + m)*72 + s*32 + quad*8];
        acc[ct] = __builtin_amdgcn_mfma_f32_16x16x32_bf16(av[s], bv, acc[ct], 0, 0, 0);
      }
    __syncthreads();
  }

  #pragma unroll
  for (int r = 0; r < 4; ++r){
    int gm = m0 + w*16 + quad*4 + r;
    #pragma unroll
    for (int ct = 0; ct < 4; ++ct){
      int gn = n0 + ct*16 + m;
      float v = acc[ct][r];
      if (bias) v += ldw(bias, gn, fl);
      v *= osc;
      if (resid) v += resid[(long)gm * ldr + gn];
      long off = (long)gm * ldc + gn;
      if (outmode == 2){
        if (fl) Cb[off] = f2bf(v); else Cf[off] = v;
      } else if (outmode == 3){
        Cb[off] = f2bf(v);
      } else {
        Cf[off] = v;
      }
      if (cdst) cdst[(long)gm * ldc + gn] = ldw(csrc, (long)gm * 256 + gn, cfl);
    }
  }
}

// ---------------- QKV extract + rotary (bf16 out; q pre-scaled by 1/8) ----
__global__ __launch_bounds__(256) void k_rope(
  const float* __restrict__ qkv, const void* __restrict__ pe,
  u16* __restrict__ q, u16* __restrict__ k, u16* __restrict__ v,
  int L, int B, int H, const int* __restrict__ flagp)
{
  int fl = *flagp;
  int tid = threadIdx.x;
  int lq = tid >> 6, d = tid & 63;
  int l = blockIdx.x * 4 + lq;
  int bh = blockIdx.y; int b = bh / H; int h = bh % H;
  const float* row = qkv + ((long)b * L + l) * 768 + h * 192;
  float qv = row[d*3+0], kv = row[d*3+1], vv = row[d*3+2];
  int dn = (d & 1) ? (d - 1) : (d + 1);
  float qn = row[dn*3+0], kn = row[dn*3+1];
  float rq = (d & 1) ? qn : -qn;
  float rk = (d & 1) ? kn : -kn;
  long peo = ((long)b * L + l) * 64 + d;
  float p0 = ldw(pe, peo, fl);
  float p1 = ldw(pe, (long)B * L * 64 + peo, fl);
  long o = ((long)bh * L + l) * 64 + d;
  q[o] = f2bf((qv * p0 + rq * p1) * 0.125f);   // exact pow2 pre-scale
  k[o] = f2bf(kv * p0 + rk * p1);
  v[o] = f2bf(vv);
}

// ---------------- MFMA flash attention, bf16 in / fp32 partials out ------
// K-split via blockIdx.z (NZ=4). Vt/Ps key-block swizzle (bank-conflict-free).
// (r12/r14/r16 verified version)
__global__ __launch_bounds__(256, 8) void k_attn_mfma(
  const u16* __restrict__ Q, long qsb, long qsh, long qsl,
  const u16* __restrict__ Kp, long ksb, long ksh, long ksl,
  const u16* __restrict__ Vp, long vsb, long vsh, long vsl,
  float* __restrict__ Opart, float* __restrict__ mpart, float* __restrict__ lpart,
  int L, int H, int kchunk)
{
  __shared__ u16 Kt[64*72];     // K tile; re-used as P tile after QK phase
  __shared__ u16 Vt[64*72];
  u16* Ps = Kt;
  const int tid  = threadIdx.x;
  const int w    = tid >> 6;
  const int lane = tid & 63;
  const int quad = lane >> 4;
  const int m    = lane & 15;
  const int bh = blockIdx.y, b = bh / H, h = bh % H;
  const int iq0 = blockIdx.x * 64;
  const int z = blockIdx.z;
  const long BHL = (long)gridDim.y * L;

  const u16* Qb = Q  + b*qsb + h*qsh;
  const u16* Kb = Kp + b*ksb + h*ksh;
  const u16* Vb = Vp + b*vsb + h*vsh;

  s16x8 aq[2];
  {
    const u16* qr = Qb + (long)(iq0 + w*16 + m) * qsl + quad*8;
    aq[0] = *(const s16x8*)(qr);
    aq[1] = *(const s16x8*)(qr + 32);
  }

  f32x4 o_acc[4];
  #pragma unroll
  for (int nt = 0; nt < 4; ++nt) o_acc[nt] = (f32x4){0.f,0.f,0.f,0.f};
  float mrow[4] = {-1e30f,-1e30f,-1e30f,-1e30f};
  float lrow[4] = {0.f,0.f,0.f,0.f};

  const int srow = tid >> 2, sc0 = (tid & 3) << 4;
  // Vt swizzled scatter offset: phys key-block = (2*(dim>>4) + key>>3) & 7
  const int vofs = ((((tid & 3) * 2 + (srow >> 3)) & 7) << 3) | (srow & 7);
  const int jend = z * kchunk + kchunk;

  for (int j0 = z * kchunk; j0 < jend; j0 += 64){
    {
      const u16* kr = Kb + (long)(j0 + srow) * ksl + sc0;
      *(uint4*)&Kt[srow*72 + sc0]     = *(const uint4*)kr;
      *(uint4*)&Kt[srow*72 + sc0 + 8] = *(const uint4*)(kr + 8);
      const u16* vr = Vb + (long)(j0 + srow) * vsl + sc0;
      #pragma unroll
      for (int g = 0; g < 2; ++g){
        ushort4 a = *(const ushort4*)(vr + g*8);
        ushort4 c = *(const ushort4*)(vr + g*8 + 4);
        Vt[(sc0 + g*8 + 0)*72 + vofs] = a.x;
        Vt[(sc0 + g*8 + 1)*72 + vofs] = a.y;
        Vt[(sc0 + g*8 + 2)*72 + vofs] = a.z;
        Vt[(sc0 + g*8 + 3)*72 + vofs] = a.w;
        Vt[(sc0 + g*8 + 4)*72 + vofs] = c.x;
        Vt[(sc0 + g*8 + 5)*72 + vofs] = c.y;
        Vt[(sc0 + g*8 + 6)*72 + vofs] = c.z;
        Vt[(sc0 + g*8 + 7)*72 + vofs] = c.w;
      }
    }
    __syncthreads();

    float sv[4][4];
    #pragma unroll
    for (int ct = 0; ct < 4; ++ct){
      f32x4 acc = (f32x4){0.f,0.f,0.f,0.f};
      #pragma unroll
      for (int s = 0; s < 2; ++s){
        s16x8 bk = *(const s16x8*)&Kt[(ct*16 + m)*72 + s*32 + quad*8];
        acc = __builtin_amdgcn_mfma_f32_16x16x32_bf16(aq[s], bk, acc, 0, 0, 0);
      }
      #pragma unroll
      for (int r = 0; r < 4; ++r) sv[ct][r] = acc[r];
    }

    float mn[4], alpha[4], rsum[4];
    #pragma unroll
    for (int r = 0; r < 4; ++r){
      float v0 = fmaxf(fmaxf(sv[0][r], sv[1][r]), fmaxf(sv[2][r], sv[3][r]));
      v0 = fmaxf(v0, __shfl_xor(v0, 1));
      v0 = fmaxf(v0, __shfl_xor(v0, 2));
      v0 = fmaxf(v0, __shfl_xor(v0, 4));
      v0 = fmaxf(v0, __shfl_xor(v0, 8));
      mn[r] = fmaxf(mrow[r], v0);
      alpha[r] = __expf(mrow[r] - mn[r]);
      mrow[r] = mn[r];
      rsum[r] = 0.f;
    }
    #pragma unroll
    for (int ct = 0; ct < 4; ++ct)
      #pragma unroll
      for (int r = 0; r < 4; ++r){
        float p = __expf(sv[ct][r] - mn[r]);
        sv[ct][r] = p;
        rsum[r] += p;
      }
    #pragma unroll
    for (int r = 0; r < 4; ++r){
      float s = rsum[r];
      s += __shfl_xor(s, 1);
      s += __shfl_xor(s, 2);
      s += __shfl_xor(s, 4);
      s += __shfl_xor(s, 8);
      lrow[r] = lrow[r] * alpha[r] + s;
    }
    #pragma unroll
    for (int nt = 0; nt < 4; ++nt)
      #pragma unroll
      for (int r = 0; r < 4; ++r) o_acc[nt][r] *= alpha[r];

    __syncthreads();   // all waves done reading Kt before P overwrites it

    // Ps swizzled write: col = ct*16+m -> phys kb = (2w + 2ct + (m>>3)) & 7
    #pragma unroll
    for (int ct = 0; ct < 4; ++ct){
      const int pofs = (((2*w + 2*ct + (m >> 3)) & 7) << 3) | (m & 7);
      #pragma unroll
      for (int r = 0; r < 4; ++r)
        Ps[(w*16 + quad*4 + r)*72 + pofs] = f2bf(sv[ct][r]);
    }
    asm volatile("s_waitcnt lgkmcnt(0)" ::: "memory");  // own-wave rows RAW

    s16x8 ap[2];
    #pragma unroll
    for (int s = 0; s < 2; ++s)
      ap[s] = *(const s16x8*)&Ps[(w*16 + m)*72 + (((2*w + 4*s + quad) & 7) << 3)];
    #pragma unroll
    for (int nt = 0; nt < 4; ++nt)
      #pragma unroll
      for (int s = 0; s < 2; ++s){
        s16x8 bv = *(const s16x8*)&Vt[(nt*16 + m)*72 + (((2*nt + 4*s + quad) & 7) << 3)];
        o_acc[nt] = __builtin_amdgcn_mfma_f32_16x16x32_bf16(ap[s], bv, o_acc[nt], 0, 0, 0);
      }
    __syncthreads();
  }

  const long zOoff = (long)z * BHL * 64;
  #pragma unroll
  for (int r = 0; r < 4; ++r){
    int iq = iq0 + w*16 + quad*4 + r;
    long rowid = ((long)b*L + iq) * H + h;
    #pragma unroll
    for (int nt = 0; nt < 4; ++nt)
      Opart[zOoff + rowid*64 + nt*16 + m] = o_acc[nt][r];
    if (m == 0){
      mpart[(long)z*BHL + rowid] = mrow[r];
      lpart[(long)z*BHL + rowid] = lrow[r];
    }
  }
}

// ---------------- attention split combine (4-way, fp32 partials) --------
__global__ __launch_bounds__(256) void k_attn_comb(
  const float* __restrict__ Opart, const float* __restrict__ mpart,
  const float* __restrict__ lpart, float* __restrict__ O, long BHL)
{
  long i = (long)blockIdx.x * 256 + threadIdx.x;
  long row = i >> 6;
  float m0 = mpart[row],         m1 = mpart[BHL + row];
  float m2 = mpart[2*BHL + row], m3 = mpart[3*BHL + row];
  float M = fmaxf(fmaxf(m0, m1), fmaxf(m2, m3));
  float w0 = __expf(m0 - M), w1 = __expf(m1 - M);
  float w2 = __expf(m2 - M), w3 = __expf(m3 - M);
  float T = lpart[row]*w0 + lpart[BHL+row]*w1 + lpart[2*BHL+row]*w2 + lpart[3*BHL+row]*w3;
  long N64 = BHL * 64;
  float acc = Opart[i]*w0 + Opart[N64 + i]*w1 + Opart[2*N64 + i]*w2 + Opart[3*N64 + i]*w3;
  O[i] = acc / T;
}

// ---------------- depthwise conv K=5 SAME + silu (x and z paths batched) --
__global__ __launch_bounds__(256) void k_conv2(
  const float* __restrict__ xz,
  const void* __restrict__ wx, const void* __restrict__ wz,
  float* __restrict__ outx, float* __restrict__ outz,
  int L, const int* __restrict__ flagp)
{
  int fl = *flagp;
  int c = threadIdx.x;
  int bl = blockIdx.x; int b = bl / L, l = bl % L;
  int choff = blockIdx.y ? 256 : 0;
  const void* w = blockIdx.y ? wz : wx;
  float* out = blockIdx.y ? outz : outx;
  const float* base = xz + ((long)b * L) * 512 + choff + c;
  float s = 0.f;
  #pragma unroll
  for (int kk = 0; kk < 5; ++kk){
    int ll = l + kk - 2;
    if (ll >= 0 && ll < L) s += base[(long)ll * 512] * ldw(w, c*5 + kk, fl);
  }
  out[((long)b * L + l) * 256 + c] = s / (1.f + __expf(-s));   // silu
}

// ---------------- chunk-parallel selective scan (xdbl ld 64) ----------------
#define SC_CS 64
#define SC_NC 32

__global__ __launch_bounds__(256) void k_scan1(
  const float* __restrict__ delta, const float* __restrict__ dxc,
  const float* __restrict__ xdbl, const void* __restrict__ Alog,
  float* __restrict__ E_out, float* __restrict__ F_out,
  int L, const int* __restrict__ flagp)
{
  int fl = *flagp;
  int tid = threadIdx.x;
  int g = tid >> 4, n = tid & 15;
  int gid = blockIdx.x * 16 + g;
  int chunk = gid & (SC_NC - 1);
  int p = gid >> 5;
  int b = p >> 8, d = p & 255;
  float A = -__expf(ldw(Alog, d*16 + n, fl));
  const float* dtp = delta + (long)b*L*256 + d;
  const float* dxp = dxc   + (long)b*L*256 + d;
  const float* xdb = xdbl + (long)b*L*64;
  int l0 = chunk * SC_CS;
  float E = 1.f, F = 0.f;
  for (int i = 0; i < SC_CS; i += 4){
    float e[4], u[4];
    #pragma unroll
    for (int j = 0; j < 4; ++j){
      int l = l0 + i + j;
      e[j] = __expf(dtp[(long)l*256] * A);
      u[j] = dxp[(long)l*256] * xdb[l*64 + 16 + n];
    }
    F = e[0]*F + u[0]; F = e[1]*F + u[1];
    F = e[2]*F + u[2]; F = e[3]*F + u[3];
    E *= (e[0]*e[1]) * (e[2]*e[3]);
  }
  long idx = (long)(p*16 + n) * SC_NC + chunk;
  E_out[idx] = E; F_out[idx] = F;
}

__global__ __launch_bounds__(256) void k_scan2(
  const float* __restrict__ E, const float* __restrict__ F,
  float* __restrict__ Hin)
{
  int pn = blockIdx.x * 256 + threadIdx.x;
  const float* Ep = E + (long)pn * SC_NC;
  const float* Fp = F + (long)pn * SC_NC;
  float* Hp = Hin + (long)pn * SC_NC;
  float h = 0.f;
  #pragma unroll
  for (int c = 0; c < SC_NC; ++c){
    Hp[c] = h;
    h = Ep[c] * h + Fp[c];
  }
}

__global__ __launch_bounds__(256) void k_scan3(
  const float* __restrict__ delta, const float* __restrict__ dxc,
  const float* __restrict__ xc, const float* __restrict__ xdbl,
  const void* __restrict__ Alog, const void* __restrict__ Dp,
  const float* __restrict__ Hin, float* __restrict__ y,
  int L, const int* __restrict__ flagp)
{
  int fl = *flagp;
  int tid = threadIdx.x;
  int g = tid >> 4, n = tid & 15;
  int gid = blockIdx.x * 16 + g;
  int chunk = gid & (SC_NC - 1);
  int p = gid >> 5;
  int b = p >> 8, d = p & 255;
  float A = -__expf(ldw(Alog, d*16 + n, fl));
  float Dv = ldw(Dp, d, fl);
  const float* dtp = delta + (long)b*L*256 + d;
  const float* dxp = dxc   + (long)b*L*256 + d;
  const float* xcb = xc    + (long)b*L*256 + d;
  const float* xdb = xdbl + (long)b*L*64;
  float* yb = y + (long)b*L*256 + d;
  long idx = (long)(p*16 + n) * SC_NC + chunk;
  float h = Hin[idx];
  int l0 = chunk * SC_CS;
  for (int i = 0; i < SC_CS; i += 4){
    float e[4], u[4], cm[4], xv[4];
    #pragma unroll
    for (int j = 0; j < 4; ++j){
      int l = l0 + i + j;
      e[j]  = __expf(dtp[(long)l*256] * A);
      u[j]  = dxp[(long)l*256] * xdb[l*64 + 16 + n];
      cm[j] = xdb[l*64 + 32 + n];
      xv[j] = xcb[(long)l*256];
    }
    float s0, s1, s2, s3;
    h = e[0]*h + u[0]; s0 = h * cm[0];
    h = e[1]*h + u[1]; s1 = h * cm[1];
    h = e[2]*h + u[2]; s2 = h * cm[2];
    h = e[3]*h + u[3]; s3 = h * cm[3];
    s0 += __shfl_xor(s0, 1, 16); s1 += __shfl_xor(s1, 1, 16);
    s2 += __shfl_xor(s2, 1, 16); s3 += __shfl_xor(s3, 1, 16);
    s0 += __shfl_xor(s0, 2, 16); s1 += __shfl_xor(s1, 2, 16);
    s2 += __shfl_xor(s2, 2, 16); s3 += __shfl_xor(s3, 2, 16);
    s0 += __shfl_xor(s0, 4, 16); s1 += __shfl_xor(s1, 4, 16);
    s2 += __shfl_xor(s2, 4, 16); s3 += __shfl_xor(s3, 4, 16);
    s0 += __shfl_xor(s0, 8, 16); s1 += __shfl_xor(s1, 8, 16);
    s2 += __shfl_xor(s2, 8, 16); s3 += __shfl_xor(s3, 8, 16);
    if (n < 4){
      float out = (n == 0) ? s0 + Dv*xv[0] : (n == 1) ? s1 + Dv*xv[1]
                : (n == 2) ? s2 + Dv*xv[2] : s3 + Dv*xv[3];
      yb[(long)(l0 + i + n)*256] = out;
    }
  }
}

// ---------------- LayerNorm over rows of 512 (in place) ----------------
__global__ __launch_bounds__(256) void k_ln(float* __restrict__ h,
                                            const void* __restrict__ g,
                                            const void* __restrict__ beta,
                                            const int* __restrict__ flagp)
{
  int fl = *flagp;
  int row = blockIdx.x * 4 + (threadIdx.x >> 6);
  int lane = threadIdx.x & 63;
  float* hr = h + (long)row * 512;
  float v[8]; float s = 0.f, ss = 0.f;
  #pragma unroll
  for (int i = 0; i < 8; ++i){ v[i] = hr[lane + 64*i]; s += v[i]; ss += v[i]*v[i]; }
  #pragma unroll
  for (int off = 1; off < 64; off <<= 1){ s += __shfl_xor(s, off); ss += __shfl_xor(ss, off); }
  float mean = s * (1.f/512.f);
  float var  = ss * (1.f/512.f) - mean * mean;
  float rs = rsqrtf(var + 1e-5f);
  #pragma unroll
  for (int i = 0; i < 8; ++i){
    int c = lane + 64*i;
    hr[c] = (v[i] - mean) * rs * ldw(g, c, fl) + ldw(beta, c, fl);
  }
}

// two-buffer LN (cross-attn i=0/1 batched)
__global__ __launch_bounds__(256) void k_ln2(float* __restrict__ hA, float* __restrict__ hB,
                                             const void* __restrict__ g,
                                             const void* __restrict__ beta,
                                             const int* __restrict__ flagp)
{
  int fl = *flagp;
  int r = blockIdx.x * 4 + (threadIdx.x >> 6);
  float* hbase = (r < 4096) ? hA : hB;
  int row = r & 4095;
  int lane = threadIdx.x & 63;
  float* hr = hbase + (long)row * 512;
  float v[8]; float s = 0.f, ss = 0.f;
  #pragma unroll
  for (int i = 0; i < 8; ++i){ v[i] = hr[lane + 64*i]; s += v[i]; ss += v[i]*v[i]; }
  #pragma unroll
  for (int off = 1; off < 64; off <<= 1){ s += __shfl_xor(s, off); ss += __shfl_xor(ss, off); }
  float mean = s * (1.f/512.f);
  float var  = ss * (1.f/512.f) - mean * mean;
  float rs = rsqrtf(var + 1e-5f);
  #pragma unroll
  for (int i = 0; i < 8; ++i){
    int c = lane + 64*i;
    hr[c] = (v[i] - mean) * rs * ldw(g, c, fl) + ldw(beta, c, fl);
  }
}

extern "C" void kernel_launch(void* const* d_in, const int* in_sizes, int n_in,
                              void* d_out, int out_size, void* d_ws, size_t ws_size,
                              hipStream_t stream)
{
  const int B_ = 2, L_ = 2048, H_ = 4;
  const long BLE = (long)B_ * L_ * 256;       // 1,048,576
  const long BHL = (long)B_ * H_ * L_;        // 16,384
  int* flagp = (int*)d_ws;
  float* base = (float*)d_ws + 64;
  float* dbuf[2] = { base + 1*BLE, base + 2*BLE };
  float* cat  = base + 3*BLE;                 // 4 BLE (attn fp32 partials / concat)
  float* qb   = base + 7*BLE;
  float* kb   = base + 8*BLE;
  float* vb   = base + 9*BLE;
  float* ob   = base + 10*BLE;
  float* hbuf = base + 11*BLE;                // 2 BLE
  float* xcb  = base + 13*BLE;
  float* zcb  = base + 14*BLE;
  float* xdbl = base + 15*BLE;                // B*L*64 = 262,144 floats
  float* mml  = xdbl + 262144;                // 4*BHL
  float* mll  = mml + 4*BHL;                  // 4*BHL
  float* px   = mll + 4*BHL;                  // 16,384 (xproj padded 64x256)
  float* pd   = px + 16384;                   // 16,384 (dt_w padded 256x64)
  float* pb   = pd + 16384;                   // 256    (dt_b fp32)

  const long SCN = (long)2 * 256 * 16 * SC_NC;
  float* scE = vb;
  float* scF = vb + SCN;
  float* scH = vb + 2*SCN;
  float* dxc = hbuf;
  float* catA = cat;
  float* catB = cat + 2*BLE;
  float* hbufB = qb;                  // 2 BLE spanning qb+kb

  const void* in[35];
  for (int i = 0; i < 35 && i < n_in; ++i) in[i] = d_in[i];

  k_sniff<<<1, 256, 0, stream>>>((const unsigned int*)in[0], 2048, flagp);
  k_pad<<<130, 256, 0, stream>>>(in[17], in[18], in[19], px, pd, pb, flagp);

  const int BIG = 1 << 30;
  // generic single GEMM: fp32 A/resid/csrc, model weights
  auto gemm = [&](const float* A, int lda, int K, int N, const void* W,
                  const void* bias, float* Cf, u16* Cb, int ldc,
                  const float* resid, int ldr, float oscale, int act, int om){
    dim3 g(N >> 6, 64);
    k_gemm_mfma<<<g, 256, 0, stream>>>(A, 1, lda, K, N, W, nullptr, BIG, 0, bias,
                                       Cf, Cb, ldc, nullptr, 0,
                                       resid, 1, ldr, nullptr, 1, nullptr,
                                       oscale, act, om, flagp);
  };

  const long sbP = (long)H_ * L_ * 64, shP = (long)L_ * 64, slP = 64;   // (B,H,L,64)
  const long sbF = (long)L_ * 256,     shF = 64,            slF = 256;  // (B,L,256)
  const dim3 gAttn(L_/64, B_*H_, 4);
  const int kchunk = L_ / 4;

  // ---------------- per-descriptor: mamba_attention ----------------
  for (int i = 0; i < 2; ++i){
    float* d = dbuf[i];
    // merged qkv (N 0..767 -> cat ld 768) + xz (768..1279 -> hbuf ld 512),
    // A = raw input (dtype-flag-aware)
    k_gemm_mfma<<<dim3(20, 64), 256, 0, stream>>>(
        in[i], 0, 256, 256, 1280, in[4], in[14], 768, 0, in[5],
        cat, nullptr, 768, hbuf, 512,
        nullptr, 1, 0, nullptr, 1, nullptr,
        1.f, 0, 0, flagp);
    k_rope<<<dim3(L_/4, B_*H_), 256, 0, stream>>>(cat, in[2+i],
        (u16*)qb, (u16*)kb, (u16*)vb, L_, B_, H_, flagp);
    k_attn_mfma<<<gAttn, 256, 0, stream>>>((u16*)qb, sbP, shP, slP,
                                           (u16*)kb, sbP, shP, slP,
                                           (u16*)vb, sbP, shP, slP,
                                           cat, mml, mll, L_, H_, kchunk);
    k_attn_comb<<<(int)(BLE/256), 256, 0, stream>>>(cat, mml, mll, ob, BHL);
    k_conv2<<<dim3(B_*L_, 2), 256, 0, stream>>>(hbuf, in[15], in[16], xcb, zcb, L_, flagp);
    // xproj (padded N=64, fp32 weights) into xdbl ld 64
    k_gemm_mfma<<<dim3(1, 64), 256, 0, stream>>>(
        xcb, 1, 256, 256, 64, px, nullptr, BIG, 1, nullptr,
        xdbl, nullptr, 64, nullptr, 0,
        nullptr, 1, 0, nullptr, 1, nullptr,
        1.f, 0, 0, flagp);
    // dt (padded K=64, fp32 weights+bias) + fused softplus -> qb, dxc
    k_gemm_mfma<<<dim3(4, 64), 256, 0, stream>>>(
        xdbl, 1, 64, 64, 256, pd, nullptr, BIG, 1, pb,
        qb, nullptr, 256, dxc, 256,
        xcb, 1, 256, nullptr, 1, nullptr,
        1.f, 0, 4, flagp);
    k_scan1<<<1024, 256, 0, stream>>>(qb, dxc, xdbl, in[20], scE, scF, L_, flagp);
    k_scan2<<<32, 256, 0, stream>>>(scE, scF, scH);
    k_scan3<<<1024, 256, 0, stream>>>(qb, dxc, xcb, xdbl, in[20], in[21], scH, kb, L_, flagp);
    // batched s_x / c_x / o-proj (+fused raw-input->cat copy) into cat (ld 1024)
    {
      GB4 gb = {};
      gb.cfl[0] = gb.cfl[1] = gb.cfl[3] = 1;
      gb.A[0] = kb;  gb.W[0] = in[22]; gb.Cf[0] = cat + 512; gb.osc[0] = 1.f;
      gb.A[1] = zcb; gb.W[1] = in[22]; gb.Cf[1] = cat + 768; gb.osc[1] = 1.f;
      gb.A[2] = ob;  gb.W[2] = in[6];  gb.bias[2] = in[7];   gb.Cf[2] = cat + 256;
      gb.csrc[2] = in[i]; gb.cdst[2] = cat; gb.osc[2] = 1.f; gb.cfl[2] = 0;
      k_gemmb<<<dim3(4, 64, 3), 256, 0, stream>>>(gb, 256, 256, 256, 1024, 0, 0, 0, flagp);
    }
    gemm(cat, 1024, 1024, 512, in[8], in[9], hbuf, nullptr, 512,
         nullptr, 0, 1.f, 0, 0);
    k_ln<<<1024, 256, 0, stream>>>(hbuf, in[10], in[11], flagp);
    // ffn2: gelu(A) @ W^T + bias + raw-input residual (dtype-flag-aware)
    k_gemm_mfma<<<dim3(4, 64), 256, 0, stream>>>(
        hbuf, 1, 512, 512, 256, in[12], nullptr, BIG, 0, in[13],
        d, nullptr, 256, nullptr, 0,
        in[i], 0, 256, nullptr, 1, nullptr,
        1.f, 1, 0, flagp);
  }

  // ---------------- cross attention ----------------
  const float s4 = 0.35355339059327373f;  // 64^-0.25
  {
    GB4 gb = {};
    gb.cfl[0] = gb.cfl[1] = gb.cfl[2] = gb.cfl[3] = 1;
    gb.A[0] = dbuf[0]; gb.W[0] = in[23]; gb.bias[0] = in[24]; gb.Cb[0] = (u16*)qb; gb.osc[0] = s4;
    gb.A[1] = dbuf[1]; gb.W[1] = in[23]; gb.bias[1] = in[24]; gb.Cb[1] = (u16*)kb; gb.osc[1] = s4;
    gb.A[2] = dbuf[0]; gb.W[2] = in[25]; gb.bias[2] = in[26]; gb.Cb[2] = (u16*)vb; gb.osc[2] = 1.f;
    gb.A[3] = dbuf[1]; gb.W[3] = in[25]; gb.bias[3] = in[26]; gb.Cb[3] = (u16*)ob; gb.osc[3] = 1.f;
    k_gemmb<<<dim3(4, 64, 4), 256, 0, stream>>>(gb, 256, 256, 256, 256, 0, 0, 3, flagp);
  }
  k_attn_mfma<<<gAttn, 256, 0, stream>>>((u16*)qb, sbF, shF, slF, (u16*)kb, sbF, shF, slF,
                                         (u16*)ob, sbF, shF, slF,
                                         cat, mml, mll, L_, H_, kchunk);
  k_attn_comb<<<(int)(BLE/256), 256, 0, stream>>>(cat, mml, mll, xcb, BHL);
  k_attn_mfma<<<gAttn, 256, 0, stream>>>((u16*)kb, sbF, shF, slF, (u16*)qb, sbF, shF, slF,
                                         (u16*)vb, sbF, shF, slF,
                                         cat, mml, mll, L_, H_, kchunk);
  k_attn_comb<<<(int)(BLE/256), 256, 0, stream>>>(cat, mml, mll, zcb, BHL);
  {
    GB4 gb = {};
    gb.cfl[0] = gb.cfl[1] = gb.cfl[2] = gb.cfl[3] = 1;
    gb.A[0] = xcb; gb.W[0] = in[27]; gb.bias[0] = in[28]; gb.Cf[0] = catA + 256;
    gb.csrc[0] = dbuf[0]; gb.cdst[0] = catA; gb.osc[0] = 1.f;
    gb.A[1] = zcb; gb.W[1] = in[27]; gb.bias[1] = in[28]; gb.Cf[1] = catB + 256;
    gb.csrc[1] = dbuf[1]; gb.cdst[1] = catB; gb.osc[1] = 1.f;
    k_gemmb<<<dim3(4, 64, 2), 256, 0, stream>>>(gb, 256, 256, 256, 512, 0, 0, 0, flagp);
  }
  {
    GB4 gb = {};
    gb.cfl[0] = gb.cfl[1] = gb.cfl[2] = gb.cfl[3] = 1;
    gb.A[0] = catA; gb.W[0] = in[29]; gb.bias[0] = in[30]; gb.Cf[0] = hbuf;  gb.osc[0] = 1.f;
    gb.A[1] = catB; gb.W[1] = in[29]; gb.bias[1] = in[30]; gb.Cf[1] = hbufB; gb.osc[1] = 1.f;
    k_gemmb<<<dim3(8, 64, 2), 256, 0, stream>>>(gb, 512, 512, 512, 512, 0, 0, 0, flagp);
  }
  k_ln2<<<2048, 256, 0, stream>>>(hbuf, hbufB, in[31], in[32], flagp);
  {
    GB4 gb = {};
    gb.cfl[0] = gb.cfl[1] = gb.cfl[2] = gb.cfl[3] = 1;
    gb.A[0] = hbuf;  gb.W[0] = in[33]; gb.bias[0] = in[34]; gb.resid[0] = dbuf[0];
    gb.Cf[0] = (float*)d_out; gb.Cb[0] = (u16*)d_out; gb.osc[0] = 1.f;
    gb.A[1] = hbufB; gb.W[1] = in[33]; gb.bias[1] = in[34]; gb.resid[1] = dbuf[1];
    gb.Cf[1] = (float*)d_out + BLE; gb.Cb[1] = (u16*)d_out + BLE; gb.osc[1] = 1.f;
    k_gemmb<<<dim3(4, 64, 2), 256, 0, stream>>>(gb, 512, 512, 256, 256, 256, 1, 2, flagp);
  }
}

// Round 18
// 876.119 us; speedup vs baseline: 1.0059x; 1.0059x over previous
//
#include <hip/hip_runtime.h>

typedef unsigned short u16;
typedef short s16;
typedef s16 s16x8 __attribute__((ext_vector_type(8)));
typedef float f32x4 __attribute__((ext_vector_type(4)));

__device__ __forceinline__ float bf2f(u16 u){
  union { unsigned int i; float f; } v; v.i = ((unsigned int)u) << 16; return v.f;
}
__device__ __forceinline__ u16 f2bf(float f){
  union { float f; unsigned int u; } v; v.f = f;
  unsigned int r = (v.u + 0x7fffu + ((v.u >> 16) & 1u)) >> 16;
  return (u16)r;
}
__device__ __forceinline__ float gelu_f(float x){
  return 0.5f * x * (1.f + erff(x * 0.70710678118654752440f));
}
__device__ __forceinline__ float ldw(const void* p, long i, int fl){
  return fl ? bf2f(((const u16*)p)[i]) : ((const float*)p)[i];
}
__device__ __forceinline__ float4 ldw4(const void* p, long i, int fl){
  if (fl){
    ushort4 w = *(const ushort4*)((const u16*)p + i);
    return make_float4(bf2f(w.x), bf2f(w.y), bf2f(w.z), bf2f(w.w));
  }
  return *(const float4*)((const float*)p + i);
}

// ---------------- dtype sniffer (flag[0]=dtype, flag[1]=0 const) --------
__global__ __launch_bounds__(256) void k_sniff(const unsigned int* __restrict__ w,
                                               int n, int* __restrict__ flag){
  __shared__ int cnt[256];
  int c = 0;
  for (int i = threadIdx.x; i < n; i += 256){
    unsigned e = (w[i] >> 7) & 0xFFu;
    c += (e >= 120u && e <= 127u) ? 1 : 0;
  }
  cnt[threadIdx.x] = c; __syncthreads();
  for (int s = 128; s > 0; s >>= 1){
    if (threadIdx.x < s) cnt[threadIdx.x] += cnt[threadIdx.x + s];
    __syncthreads();
  }
  if (threadIdx.x == 0) flag[0] = (2 * cnt[0] > n) ? 1 : 0;
  if (threadIdx.x == 1) flag[1] = 0;
}

// ---- zero-pad xproj (48x256 -> 64x256) / dt_w (256x16 -> 256x64) / dt_b ----
__global__ __launch_bounds__(256) void k_pad(
  const void* __restrict__ wx, const void* __restrict__ wd,
  const void* __restrict__ bd,
  float* __restrict__ px, float* __restrict__ pd, float* __restrict__ pb,
  const int* __restrict__ flagp)
{
  int fl = *flagp;
  int i = blockIdx.x * 256 + threadIdx.x;
  if (i < 16384){
    int r = i >> 8, c = i & 255;
    px[i] = (r < 48) ? ldw(wx, r*256 + c, fl) : 0.f;
  } else if (i < 32768){
    int j = i - 16384;
    int n = j >> 6, k = j & 63;
    pd[j] = (k < 16) ? ldw(wd, n*16 + k, fl) : 0.f;
  } else if (i < 33024){
    pb[i - 32768] = ldw(bd, i - 32768, fl);
  }
}

// ---------------- MFMA GEMM ----------------
// Flag indices select dtype per stream: flagp[idx] (0=input dtype, 1=fp32).
// outmode: 0 fp32, 2 dynamic, 3 bf16, 4 softplus(dt+2*bias) -> Cf, *xc -> C2.
__global__ __launch_bounds__(256) void k_gemm_mfma(
  const void* __restrict__ A, int aflidx, int lda, int K, int N,
  const void* __restrict__ W, const void* __restrict__ W2, int nsplit, int wflidx,
  const void* __restrict__ bias,
  float* __restrict__ Cf, u16* __restrict__ Cb, int ldc,
  float* __restrict__ C2, int ldc2,
  const void* __restrict__ resid, int rflidx, int ldr,
  const void* __restrict__ csrc, int cflidx, float* __restrict__ cdst,
  float oscale, int act_gelu, int outmode, const int* __restrict__ flagp)
{
  const int fl  = flagp[0];
  const int afl = flagp[aflidx];
  const int wfl = flagp[wflidx];
  const int rfl = flagp[rflidx];
  const int cfl = flagp[cflidx];
  __shared__ u16 As[64*72];
  __shared__ u16 Bs[64*72];
  const int tid = threadIdx.x;
  const int w = tid >> 6, lane = tid & 63, quad = lane >> 4, m = lane & 15;
  const int m0 = blockIdx.y << 6, n0 = blockIdx.x << 6;
  const int srow = tid >> 2, sc0 = (tid & 3) << 4;
  const int reg2 = (n0 >= nsplit);
  const void* Wp = reg2 ? W2 : W;
  const int nbase = reg2 ? nsplit : 0;

  f32x4 acc[4];
  #pragma unroll
  for (int ct = 0; ct < 4; ++ct) acc[ct] = (f32x4){0.f,0.f,0.f,0.f};

  for (int k0 = 0; k0 < K; k0 += 64){
    {
      long ab = (long)(m0 + srow) * lda + k0 + sc0;
      #pragma unroll
      for (int g = 0; g < 2; ++g){
        float4 a0 = ldw4(A, ab + g*8, afl);
        float4 a1 = ldw4(A, ab + g*8 + 4, afl);
        if (act_gelu){
          a0.x=gelu_f(a0.x); a0.y=gelu_f(a0.y); a0.z=gelu_f(a0.z); a0.w=gelu_f(a0.w);
          a1.x=gelu_f(a1.x); a1.y=gelu_f(a1.y); a1.z=gelu_f(a1.z); a1.w=gelu_f(a1.w);
        }
        union { u16 h[8]; uint4 v; } pk;
        pk.h[0]=f2bf(a0.x); pk.h[1]=f2bf(a0.y); pk.h[2]=f2bf(a0.z); pk.h[3]=f2bf(a0.w);
        pk.h[4]=f2bf(a1.x); pk.h[5]=f2bf(a1.y); pk.h[6]=f2bf(a1.z); pk.h[7]=f2bf(a1.w);
        *(uint4*)&As[srow*72 + sc0 + g*8] = pk.v;
      }
    }
    {
      long wb = (long)(n0 + srow - nbase) * K + k0 + sc0;
      #pragma unroll
      for (int g = 0; g < 2; ++g){
        float4 b0 = ldw4(Wp, wb + g*8, wfl);
        float4 b1 = ldw4(Wp, wb + g*8 + 4, wfl);
        union { u16 h[8]; uint4 v; } pk;
        pk.h[0]=f2bf(b0.x); pk.h[1]=f2bf(b0.y); pk.h[2]=f2bf(b0.z); pk.h[3]=f2bf(b0.w);
        pk.h[4]=f2bf(b1.x); pk.h[5]=f2bf(b1.y); pk.h[6]=f2bf(b1.z); pk.h[7]=f2bf(b1.w);
        *(uint4*)&Bs[srow*72 + sc0 + g*8] = pk.v;
      }
    }
    __syncthreads();

    s16x8 av[2];
    #pragma unroll
    for (int s = 0; s < 2; ++s)
      av[s] = *(const s16x8*)&As[(w*16 + m)*72 + s*32 + quad*8];
    #pragma unroll
    for (int ct = 0; ct < 4; ++ct)
      #pragma unroll
      for (int s = 0; s < 2; ++s){
        s16x8 bv = *(const s16x8*)&Bs[(ct*16 + m)*72 + s*32 + quad*8];
        acc[ct] = __builtin_amdgcn_mfma_f32_16x16x32_bf16(av[s], bv, acc[ct], 0, 0, 0);
      }
    __syncthreads();
  }

  #pragma unroll
  for (int r = 0; r < 4; ++r){
    int gm = m0 + w*16 + quad*4 + r;
    #pragma unroll
    for (int ct = 0; ct < 4; ++ct){
      int gn = n0 + ct*16 + m;
      float v = acc[ct][r];
      if (reg2){
        C2[(long)gm * ldc2 + (gn - nsplit)] = v;
      } else if (outmode == 4){
        float bv = ldw(bias, gn, wfl);
        float dl = v + bv + bv;              // dt + 2*dt_bias (ref's double add)
        float delta = (dl > 20.f) ? dl : __logf(1.f + __expf(dl));
        Cf[(long)gm * ldc + gn] = delta;
        C2[(long)gm * ldc2 + gn] = delta * ldw(resid, (long)gm * ldr + gn, rfl);
      } else {
        if (bias) v += ldw(bias, gn, wfl);
        v *= oscale;
        if (resid) v += ldw(resid, (long)gm * ldr + gn, rfl);
        long off = (long)gm * ldc + gn;
        if (outmode == 2){
          if (fl) Cb[off] = f2bf(v); else Cf[off] = v;
        } else if (outmode == 3){
          Cb[off] = f2bf(v);
        } else {
          Cf[off] = v;
        }
        if (cdst) cdst[(long)gm * ldc + gn] = ldw(csrc, (long)gm * 256 + gn, cfl);
      }
    }
  }
}

// ---------------- z-batched MFMA GEMM (up to 4 independent problems) ----------------
// ldwq = weight row stride (elements); wkoff = per-z weight k-offset (split-K).
struct GB4 {
  const float* A[4]; const void* W[4]; const void* bias[4];
  float* Cf[4]; u16* Cb[4]; const float* resid[4];
  const void* csrc[4]; float* cdst[4]; float osc[4]; int cfl[4]; int wkoff[4];
};

__global__ __launch_bounds__(256) void k_gemmb(
  GB4 gb, int lda, int K, int N, int ldc, int ldr, int ldwq,
  int act_gelu, int outmode, const int* __restrict__ flagp)
{
  const int fl = flagp[0];
  const int z = blockIdx.z;
  const float* A = gb.A[z]; const void* W = gb.W[z]; const void* bias = gb.bias[z];
  float* Cf = gb.Cf[z]; u16* Cb = gb.Cb[z]; const float* resid = gb.resid[z];
  const void* csrc = gb.csrc[z]; float* cdst = gb.cdst[z];
  const float osc = gb.osc[z];
  const int cfl = flagp[gb.cfl[z]];
  const int wkoff = gb.wkoff[z];

  __shared__ u16 As[64*72];
  __shared__ u16 Bs[64*72];
  const int tid = threadIdx.x;
  const int w = tid >> 6, lane = tid & 63, quad = lane >> 4, m = lane & 15;
  const int m0 = blockIdx.y << 6, n0 = blockIdx.x << 6;
  const int srow = tid >> 2, sc0 = (tid & 3) << 4;

  f32x4 acc[4];
  #pragma unroll
  for (int ct = 0; ct < 4; ++ct) acc[ct] = (f32x4){0.f,0.f,0.f,0.f};

  for (int k0 = 0; k0 < K; k0 += 64){
    {
      const float* ar = A + (long)(m0 + srow) * lda + k0 + sc0;
      #pragma unroll
      for (int g = 0; g < 2; ++g){
        float4 a0 = *(const float4*)(ar + g*8);
        float4 a1 = *(const float4*)(ar + g*8 + 4);
        if (act_gelu){
          a0.x=gelu_f(a0.x); a0.y=gelu_f(a0.y); a0.z=gelu_f(a0.z); a0.w=gelu_f(a0.w);
          a1.x=gelu_f(a1.x); a1.y=gelu_f(a1.y); a1.z=gelu_f(a1.z); a1.w=gelu_f(a1.w);
        }
        union { u16 h[8]; uint4 v; } pk;
        pk.h[0]=f2bf(a0.x); pk.h[1]=f2bf(a0.y); pk.h[2]=f2bf(a0.z); pk.h[3]=f2bf(a0.w);
        pk.h[4]=f2bf(a1.x); pk.h[5]=f2bf(a1.y); pk.h[6]=f2bf(a1.z); pk.h[7]=f2bf(a1.w);
        *(uint4*)&As[srow*72 + sc0 + g*8] = pk.v;
      }
    }
    {
      long wb = (long)(n0 + srow) * ldwq + wkoff + k0 + sc0;
      #pragma unroll
      for (int g = 0; g < 2; ++g){
        float4 b0 = ldw4(W, wb + g*8, fl);
        float4 b1 = ldw4(W, wb + g*8 + 4, fl);
        union { u16 h[8]; uint4 v; } pk;
        pk.h[0]=f2bf(b0.x); pk.h[1]=f2bf(b0.y); pk.h[2]=f2bf(b0.z); pk.h[3]=f2bf(b0.w);
        pk.h[4]=f2bf(b1.x); pk.h[5]=f2bf(b1.y); pk.h[6]=f2bf(b1.z); pk.h[7]=f2bf(b1.w);
        *(uint4*)&Bs[srow*72 + sc0 + g*8] = pk.v;
      }
    }
    __syncthreads();

    s16x8 av[2];
    #pragma unroll
    for (int s = 0; s < 2; ++s)
      av[s] = *(const s16x8*)&As[(w*16 + m)*72 + s*32 + quad*8];
    #pragma unroll
    for (int ct = 0; ct < 4; ++ct)
      #pragma unroll
      for (int s = 0; s < 2; ++s){
        s16x8 bv = *(const s16x8*)&Bs[(ct*16 + m)*72 + s*32 + quad*8];
        acc[ct] = __builtin_amdgcn_mfma_f32_16x16x32_bf16(av[s], bv, acc[ct], 0, 0, 0);
      }
    __syncthreads();
  }

  #pragma unroll
  for (int r = 0; r < 4; ++r){
    int gm = m0 + w*16 + quad*4 + r;
    #pragma unroll
    for (int ct = 0; ct < 4; ++ct){
      int gn = n0 + ct*16 + m;
      float v = acc[ct][r];
      if (bias) v += ldw(bias, gn, fl);
      v *= osc;
      if (resid) v += resid[(long)gm * ldr + gn];
      long off = (long)gm * ldc + gn;
      if (outmode == 2){
        if (fl) Cb[off] = f2bf(v); else Cf[off] = v;
      } else if (outmode == 3){
        Cb[off] = f2bf(v);
      } else {
        Cf[off] = v;
      }
      if (cdst) cdst[(long)gm * ldc + gn] = ldw(csrc, (long)gm * 256 + gn, cfl);
    }
  }
}

// ---------------- QKV extract + rotary (bf16 out; q pre-scaled by 1/8) ----
__global__ __launch_bounds__(256) void k_rope(
  const float* __restrict__ qkv, const void* __restrict__ pe,
  u16* __restrict__ q, u16* __restrict__ k, u16* __restrict__ v,
  int L, int B, int H, const int* __restrict__ flagp)
{
  int fl = *flagp;
  int tid = threadIdx.x;
  int lq = tid >> 6, d = tid & 63;
  int l = blockIdx.x * 4 + lq;
  int bh = blockIdx.y; int b = bh / H; int h = bh % H;
  const float* row = qkv + ((long)b * L + l) * 768 + h * 192;
  float qv = row[d*3+0], kv = row[d*3+1], vv = row[d*3+2];
  int dn = (d & 1) ? (d - 1) : (d + 1);
  float qn = row[dn*3+0], kn = row[dn*3+1];
  float rq = (d & 1) ? qn : -qn;
  float rk = (d & 1) ? kn : -kn;
  long peo = ((long)b * L + l) * 64 + d;
  float p0 = ldw(pe, peo, fl);
  float p1 = ldw(pe, (long)B * L * 64 + peo, fl);
  long o = ((long)bh * L + l) * 64 + d;
  q[o] = f2bf((qv * p0 + rq * p1) * 0.125f);   // exact pow2 pre-scale
  k[o] = f2bf(kv * p0 + rk * p1);
  v[o] = f2bf(vv);
}

// ---------------- MFMA flash attention, bf16 in / fp32 partials out ------
// K-split via blockIdx.z (NZ=4). Vt/Ps key-block swizzle (bank-conflict-free).
__global__ __launch_bounds__(256, 8) void k_attn_mfma(
  const u16* __restrict__ Q, long qsb, long qsh, long qsl,
  const u16* __restrict__ Kp, long ksb, long ksh, long ksl,
  const u16* __restrict__ Vp, long vsb, long vsh, long vsl,
  float* __restrict__ Opart, float* __restrict__ mpart, float* __restrict__ lpart,
  int L, int H, int kchunk)
{
  __shared__ u16 Kt[64*72];     // K tile; re-used as P tile after QK phase
  __shared__ u16 Vt[64*72];
  u16* Ps = Kt;
  const int tid  = threadIdx.x;
  const int w    = tid >> 6;
  const int lane = tid & 63;
  const int quad = lane >> 4;
  const int m    = lane & 15;
  const int bh = blockIdx.y, b = bh / H, h = bh % H;
  const int iq0 = blockIdx.x * 64;
  const int z = blockIdx.z;
  const long BHL = (long)gridDim.y * L;

  const u16* Qb = Q  + b*qsb + h*qsh;
  const u16* Kb = Kp + b*ksb + h*ksh;
  const u16* Vb = Vp + b*vsb + h*vsh;

  s16x8 aq[2];
  {
    const u16* qr = Qb + (long)(iq0 + w*16 + m) * qsl + quad*8;
    aq[0] = *(const s16x8*)(qr);
    aq[1] = *(const s16x8*)(qr + 32);
  }

  f32x4 o_acc[4];
  #pragma unroll
  for (int nt = 0; nt < 4; ++nt) o_acc[nt] = (f32x4){0.f,0.f,0.f,0.f};
  float mrow[4] = {-1e30f,-1e30f,-1e30f,-1e30f};
  float lrow[4] = {0.f,0.f,0.f,0.f};

  const int srow = tid >> 2, sc0 = (tid & 3) << 4;
  // Vt swizzled scatter offset: phys key-block = (2*(dim>>4) + key>>3) & 7
  const int vofs = ((((tid & 3) * 2 + (srow >> 3)) & 7) << 3) | (srow & 7);
  const int jend = z * kchunk + kchunk;

  for (int j0 = z * kchunk; j0 < jend; j0 += 64){
    {
      const u16* kr = Kb + (long)(j0 + srow) * ksl + sc0;
      *(uint4*)&Kt[srow*72 + sc0]     = *(const uint4*)kr;
      *(uint4*)&Kt[srow*72 + sc0 + 8] = *(const uint4*)(kr + 8);
      const u16* vr = Vb + (long)(j0 + srow) * vsl + sc0;
      #pragma unroll
      for (int g = 0; g < 2; ++g){
        ushort4 a = *(const ushort4*)(vr + g*8);
        ushort4 c = *(const ushort4*)(vr + g*8 + 4);
        Vt[(sc0 + g*8 + 0)*72 + vofs] = a.x;
        Vt[(sc0 + g*8 + 1)*72 + vofs] = a.y;
        Vt[(sc0 + g*8 + 2)*72 + vofs] = a.z;
        Vt[(sc0 + g*8 + 3)*72 + vofs] = a.w;
        Vt[(sc0 + g*8 + 4)*72 + vofs] = c.x;
        Vt[(sc0 + g*8 + 5)*72 + vofs] = c.y;
        Vt[(sc0 + g*8 + 6)*72 + vofs] = c.z;
        Vt[(sc0 + g*8 + 7)*72 + vofs] = c.w;
      }
    }
    __syncthreads();

    float sv[4][4];
    #pragma unroll
    for (int ct = 0; ct < 4; ++ct){
      f32x4 acc = (f32x4){0.f,0.f,0.f,0.f};
      #pragma unroll
      for (int s = 0; s < 2; ++s){
        s16x8 bk = *(const s16x8*)&Kt[(ct*16 + m)*72 + s*32 + quad*8];
        acc = __builtin_amdgcn_mfma_f32_16x16x32_bf16(aq[s], bk, acc, 0, 0, 0);
      }
      #pragma unroll
      for (int r = 0; r < 4; ++r) sv[ct][r] = acc[r];
    }

    float mn[4], alpha[4], rsum[4];
    #pragma unroll
    for (int r = 0; r < 4; ++r){
      float v0 = fmaxf(fmaxf(sv[0][r], sv[1][r]), fmaxf(sv[2][r], sv[3][r]));
      v0 = fmaxf(v0, __shfl_xor(v0, 1));
      v0 = fmaxf(v0, __shfl_xor(v0, 2));
      v0 = fmaxf(v0, __shfl_xor(v0, 4));
      v0 = fmaxf(v0, __shfl_xor(v0, 8));
      mn[r] = fmaxf(mrow[r], v0);
      alpha[r] = __expf(mrow[r] - mn[r]);
      mrow[r] = mn[r];
      rsum[r] = 0.f;
    }
    #pragma unroll
    for (int ct = 0; ct < 4; ++ct)
      #pragma unroll
      for (int r = 0; r < 4; ++r){
        float p = __expf(sv[ct][r] - mn[r]);
        sv[ct][r] = p;
        rsum[r] += p;
      }
    #pragma unroll
    for (int r = 0; r < 4; ++r){
      float s = rsum[r];
      s += __shfl_xor(s, 1);
      s += __shfl_xor(s, 2);
      s += __shfl_xor(s, 4);
      s += __shfl_xor(s, 8);
      lrow[r] = lrow[r] * alpha[r] + s;
    }
    #pragma unroll
    for (int nt = 0; nt < 4; ++nt)
      #pragma unroll
      for (int r = 0; r < 4; ++r) o_acc[nt][r] *= alpha[r];

    __syncthreads();   // all waves done reading Kt before P overwrites it

    // Ps swizzled write: col = ct*16+m -> phys kb = (2w + 2ct + (m>>3)) & 7
    #pragma unroll
    for (int ct = 0; ct < 4; ++ct){
      const int pofs = (((2*w + 2*ct + (m >> 3)) & 7) << 3) | (m & 7);
      #pragma unroll
      for (int r = 0; r < 4; ++r)
        Ps[(w*16 + quad*4 + r)*72 + pofs] = f2bf(sv[ct][r]);
    }
    asm volatile("s_waitcnt lgkmcnt(0)" ::: "memory");  // own-wave rows RAW

    s16x8 ap[2];
    #pragma unroll
    for (int s = 0; s < 2; ++s)
      ap[s] = *(const s16x8*)&Ps[(w*16 + m)*72 + (((2*w + 4*s + quad) & 7) << 3)];
    #pragma unroll
    for (int nt = 0; nt < 4; ++nt)
      #pragma unroll
      for (int s = 0; s < 2; ++s){
        s16x8 bv = *(const s16x8*)&Vt[(nt*16 + m)*72 + (((2*nt + 4*s + quad) & 7) << 3)];
        o_acc[nt] = __builtin_amdgcn_mfma_f32_16x16x32_bf16(ap[s], bv, o_acc[nt], 0, 0, 0);
      }
    __syncthreads();
  }

  const long zOoff = (long)z * BHL * 64;
  #pragma unroll
  for (int r = 0; r < 4; ++r){
    int iq = iq0 + w*16 + quad*4 + r;
    long rowid = ((long)b*L + iq) * H + h;
    #pragma unroll
    for (int nt = 0; nt < 4; ++nt)
      Opart[zOoff + rowid*64 + nt*16 + m] = o_acc[nt][r];
    if (m == 0){
      mpart[(long)z*BHL + rowid] = mrow[r];
      lpart[(long)z*BHL + rowid] = lrow[r];
    }
  }
}

// ---------------- attention split combine (4-way, fp32 partials) --------
__global__ __launch_bounds__(256) void k_attn_comb(
  const float* __restrict__ Opart, const float* __restrict__ mpart,
  const float* __restrict__ lpart, float* __restrict__ O, long BHL)
{
  long i = (long)blockIdx.x * 256 + threadIdx.x;
  long row = i >> 6;
  float m0 = mpart[row],         m1 = mpart[BHL + row];
  float m2 = mpart[2*BHL + row], m3 = mpart[3*BHL + row];
  float M = fmaxf(fmaxf(m0, m1), fmaxf(m2, m3));
  float w0 = __expf(m0 - M), w1 = __expf(m1 - M);
  float w2 = __expf(m2 - M), w3 = __expf(m3 - M);
  float T = lpart[row]*w0 + lpart[BHL+row]*w1 + lpart[2*BHL+row]*w2 + lpart[3*BHL+row]*w3;
  long N64 = BHL * 64;
  float acc = Opart[i]*w0 + Opart[N64 + i]*w1 + Opart[2*N64 + i]*w2 + Opart[3*N64 + i]*w3;
  O[i] = acc / T;
}

// ---------------- depthwise conv K=5 SAME + silu (x and z paths batched) --
__global__ __launch_bounds__(256) void k_conv2(
  const float* __restrict__ xz,
  const void* __restrict__ wx, const void* __restrict__ wz,
  float* __restrict__ outx, float* __restrict__ outz,
  int L, const int* __restrict__ flagp)
{
  int fl = *flagp;
  int c = threadIdx.x;
  int bl = blockIdx.x; int b = bl / L, l = bl % L;
  int choff = blockIdx.y ? 256 : 0;
  const void* w = blockIdx.y ? wz : wx;
  float* out = blockIdx.y ? outz : outx;
  const float* base = xz + ((long)b * L) * 512 + choff + c;
  float s = 0.f;
  #pragma unroll
  for (int kk = 0; kk < 5; ++kk){
    int ll = l + kk - 2;
    if (ll >= 0 && ll < L) s += base[(long)ll * 512] * ldw(w, c*5 + kk, fl);
  }
  out[((long)b * L + l) * 256 + c] = s / (1.f + __expf(-s));   // silu
}

// ---------------- chunk-parallel selective scan (xdbl ld 64) ----------------
#define SC_CS 64
#define SC_NC 32

__global__ __launch_bounds__(256) void k_scan1(
  const float* __restrict__ delta, const float* __restrict__ dxc,
  const float* __restrict__ xdbl, const void* __restrict__ Alog,
  float* __restrict__ E_out, float* __restrict__ F_out,
  int L, const int* __restrict__ flagp)
{
  int fl = *flagp;
  int tid = threadIdx.x;
  int g = tid >> 4, n = tid & 15;
  int gid = blockIdx.x * 16 + g;
  int chunk = gid & (SC_NC - 1);
  int p = gid >> 5;
  int b = p >> 8, d = p & 255;
  float A = -__expf(ldw(Alog, d*16 + n, fl));
  const float* dtp = delta + (long)b*L*256 + d;
  const float* dxp = dxc   + (long)b*L*256 + d;
  const float* xdb = xdbl + (long)b*L*64;
  int l0 = chunk * SC_CS;
  float E = 1.f, F = 0.f;
  for (int i = 0; i < SC_CS; i += 4){
    float e[4], u[4];
    #pragma unroll
    for (int j = 0; j < 4; ++j){
      int l = l0 + i + j;
      e[j] = __expf(dtp[(long)l*256] * A);
      u[j] = dxp[(long)l*256] * xdb[l*64 + 16 + n];
    }
    F = e[0]*F + u[0]; F = e[1]*F + u[1];
    F = e[2]*F + u[2]; F = e[3]*F + u[3];
    E *= (e[0]*e[1]) * (e[2]*e[3]);
  }
  long idx = (long)(p*16 + n) * SC_NC + chunk;
  E_out[idx] = E; F_out[idx] = F;
}

__global__ __launch_bounds__(256) void k_scan2(
  const float* __restrict__ E, const float* __restrict__ F,
  float* __restrict__ Hin)
{
  int pn = blockIdx.x * 256 + threadIdx.x;
  const float* Ep = E + (long)pn * SC_NC;
  const float* Fp = F + (long)pn * SC_NC;
  float* Hp = Hin + (long)pn * SC_NC;
  float h = 0.f;
  #pragma unroll
  for (int c = 0; c < SC_NC; ++c){
    Hp[c] = h;
    h = Ep[c] * h + Fp[c];
  }
}

__global__ __launch_bounds__(256) void k_scan3(
  const float* __restrict__ delta, const float* __restrict__ dxc,
  const float* __restrict__ xc, const float* __restrict__ xdbl,
  const void* __restrict__ Alog, const void* __restrict__ Dp,
  const float* __restrict__ Hin, float* __restrict__ y,
  int L, const int* __restrict__ flagp)
{
  int fl = *flagp;
  int tid = threadIdx.x;
  int g = tid >> 4, n = tid & 15;
  int gid = blockIdx.x * 16 + g;
  int chunk = gid & (SC_NC - 1);
  int p = gid >> 5;
  int b = p >> 8, d = p & 255;
  float A = -__expf(ldw(Alog, d*16 + n, fl));
  float Dv = ldw(Dp, d, fl);
  const float* dtp = delta + (long)b*L*256 + d;
  const float* dxp = dxc   + (long)b*L*256 + d;
  const float* xcb = xc    + (long)b*L*256 + d;
  const float* xdb = xdbl + (long)b*L*64;
  float* yb = y + (long)b*L*256 + d;
  long idx = (long)(p*16 + n) * SC_NC + chunk;
  float h = Hin[idx];
  int l0 = chunk * SC_CS;
  for (int i = 0; i < SC_CS; i += 4){
    float e[4], u[4], cm[4], xv[4];
    #pragma unroll
    for (int j = 0; j < 4; ++j){
      int l = l0 + i + j;
      e[j]  = __expf(dtp[(long)l*256] * A);
      u[j]  = dxp[(long)l*256] * xdb[l*64 + 16 + n];
      cm[j] = xdb[l*64 + 32 + n];
      xv[j] = xcb[(long)l*256];
    }
    float s0, s1, s2, s3;
    h = e[0]*h + u[0]; s0 = h * cm[0];
    h = e[1]*h + u[1]; s1 = h * cm[1];
    h = e[2]*h + u[2]; s2 = h * cm[2];
    h = e[3]*h + u[3]; s3 = h * cm[3];
    s0 += __shfl_xor(s0, 1, 16); s1 += __shfl_xor(s1, 1, 16);
    s2 += __shfl_xor(s2, 1, 16); s3 += __shfl_xor(s3, 1, 16);
    s0 += __shfl_xor(s0, 2, 16); s1 += __shfl_xor(s1, 2, 16);
    s2 += __shfl_xor(s2, 2, 16); s3 += __shfl_xor(s3, 2, 16);
    s0 += __shfl_xor(s0, 4, 16); s1 += __shfl_xor(s1, 4, 16);
    s2 += __shfl_xor(s2, 4, 16); s3 += __shfl_xor(s3, 4, 16);
    s0 += __shfl_xor(s0, 8, 16); s1 += __shfl_xor(s1, 8, 16);
    s2 += __shfl_xor(s2, 8, 16); s3 += __shfl_xor(s3, 8, 16);
    if (n < 4){
      float out = (n == 0) ? s0 + Dv*xv[0] : (n == 1) ? s1 + Dv*xv[1]
                : (n == 2) ? s2 + Dv*xv[2] : s3 + Dv*xv[3];
      yb[(long)(l0 + i + n)*256] = out;
    }
  }
}

// ---------------- LayerNorm over rows of 512 (h += h2 partial, in place) --
__global__ __launch_bounds__(256) void k_ln(float* __restrict__ h,
                                            const float* __restrict__ h2,
                                            const void* __restrict__ g,
                                            const void* __restrict__ beta,
                                            const int* __restrict__ flagp)
{
  int fl = *flagp;
  int row = blockIdx.x * 4 + (threadIdx.x >> 6);
  int lane = threadIdx.x & 63;
  float* hr = h + (long)row * 512;
  const float* h2r = h2 + (long)row * 512;
  float v[8]; float s = 0.f, ss = 0.f;
  #pragma unroll
  for (int i = 0; i < 8; ++i){
    v[i] = hr[lane + 64*i] + h2r[lane + 64*i];
    s += v[i]; ss += v[i]*v[i];
  }
  #pragma unroll
  for (int off = 1; off < 64; off <<= 1){ s += __shfl_xor(s, off); ss += __shfl_xor(ss, off); }
  float mean = s * (1.f/512.f);
  float var  = ss * (1.f/512.f) - mean * mean;
  float rs = rsqrtf(var + 1e-5f);
  #pragma unroll
  for (int i = 0; i < 8; ++i){
    int c = lane + 64*i;
    hr[c] = (v[i] - mean) * rs * ldw(g, c, fl) + ldw(beta, c, fl);
  }
}

// two-buffer LN with split-K partial sum (cross-attn i=0/1 batched)
__global__ __launch_bounds__(256) void k_ln2(
  float* __restrict__ hA, const float* __restrict__ hA2,
  float* __restrict__ hB, const float* __restrict__ hB2,
  const void* __restrict__ g, const void* __restrict__ beta,
  const int* __restrict__ flagp)
{
  int fl = *flagp;
  int r = blockIdx.x * 4 + (threadIdx.x >> 6);
  float* hbase = (r < 4096) ? hA : hB;
  const float* h2base = (r < 4096) ? hA2 : hB2;
  int row = r & 4095;
  int lane = threadIdx.x & 63;
  float* hr = hbase + (long)row * 512;
  const float* h2r = h2base + (long)row * 512;
  float v[8]; float s = 0.f, ss = 0.f;
  #pragma unroll
  for (int i = 0; i < 8; ++i){
    v[i] = hr[lane + 64*i] + h2r[lane + 64*i];
    s += v[i]; ss += v[i]*v[i];
  }
  #pragma unroll
  for (int off = 1; off < 64; off <<= 1){ s += __shfl_xor(s, off); ss += __shfl_xor(ss, off); }
  float mean = s * (1.f/512.f);
  float var  = ss * (1.f/512.f) - mean * mean;
  float rs = rsqrtf(var + 1e-5f);
  #pragma unroll
  for (int i = 0; i < 8; ++i){
    int c = lane + 64*i;
    hr[c] = (v[i] - mean) * rs * ldw(g, c, fl) + ldw(beta, c, fl);
  }
}

extern "C" void kernel_launch(void* const* d_in, const int* in_sizes, int n_in,
                              void* d_out, int out_size, void* d_ws, size_t ws_size,
                              hipStream_t stream)
{
  const int B_ = 2, L_ = 2048, H_ = 4;
  const long BLE = (long)B_ * L_ * 256;       // 1,048,576
  const long BHL = (long)B_ * H_ * L_;        // 16,384
  int* flagp = (int*)d_ws;
  float* base = (float*)d_ws + 64;
  float* dbuf[2] = { base + 1*BLE, base + 2*BLE };
  float* cat  = base + 3*BLE;                 // 4 BLE (attn fp32 partials / concat)
  float* qb   = base + 7*BLE;
  float* kb   = base + 8*BLE;
  float* vb   = base + 9*BLE;
  float* ob   = base + 10*BLE;
  float* hbuf = base + 11*BLE;                // 2 BLE
  float* xcb  = base + 13*BLE;
  float* zcb  = base + 14*BLE;
  float* xdbl = base + 15*BLE;                // B*L*64 = 262,144 floats
  float* mml  = xdbl + 262144;                // 4*BHL
  float* mll  = mml + 4*BHL;                  // 4*BHL
  float* px   = mll + 4*BHL;                  // 16,384 (xproj padded 64x256)
  float* pd   = px + 16384;                   // 16,384 (dt_w padded 256x64)
  float* pb   = pd + 16384;                   // 256    (dt_b fp32)

  const long SCN = (long)2 * 256 * 16 * SC_NC;
  float* scE = vb;
  float* scF = vb + SCN;
  float* scH = vb + 2*SCN;
  float* dxc = hbuf;
  float* catA = cat;
  float* catB = cat + 2*BLE;
  float* hbufB = qb;                  // 2 BLE spanning qb+kb
  float* partM = xcb;                 // 2 BLE spanning xcb+zcb (mamba ffn1 partial)
  float* partB = vb;                  // 2 BLE spanning vb+ob (ca ffn1 B partial)

  const void* in[35];
  for (int i = 0; i < 35 && i < n_in; ++i) in[i] = d_in[i];

  k_sniff<<<1, 256, 0, stream>>>((const unsigned int*)in[0], 2048, flagp);
  k_pad<<<130, 256, 0, stream>>>(in[17], in[18], in[19], px, pd, pb, flagp);

  const int BIG = 1 << 30;
  const long sbP = (long)H_ * L_ * 64, shP = (long)L_ * 64, slP = 64;   // (B,H,L,64)
  const long sbF = (long)L_ * 256,     shF = 64,            slF = 256;  // (B,L,256)
  const dim3 gAttn(L_/64, B_*H_, 4);
  const int kchunk = L_ / 4;

  // ---------------- per-descriptor: mamba_attention ----------------
  for (int i = 0; i < 2; ++i){
    float* d = dbuf[i];
    // merged qkv (N 0..767 -> cat ld 768) + xz (768..1279 -> hbuf ld 512)
    k_gemm_mfma<<<dim3(20, 64), 256, 0, stream>>>(
        in[i], 0, 256, 256, 1280, in[4], in[14], 768, 0, in[5],
        cat, nullptr, 768, hbuf, 512,
        nullptr, 1, 0, nullptr, 1, nullptr,
        1.f, 0, 0, flagp);
    k_rope<<<dim3(L_/4, B_*H_), 256, 0, stream>>>(cat, in[2+i],
        (u16*)qb, (u16*)kb, (u16*)vb, L_, B_, H_, flagp);
    k_attn_mfma<<<gAttn, 256, 0, stream>>>((u16*)qb, sbP, shP, slP,
                                           (u16*)kb, sbP, shP, slP,
                                           (u16*)vb, sbP, shP, slP,
                                           cat, mml, mll, L_, H_, kchunk);
    k_attn_comb<<<(int)(BLE/256), 256, 0, stream>>>(cat, mml, mll, ob, BHL);
    k_conv2<<<dim3(B_*L_, 2), 256, 0, stream>>>(hbuf, in[15], in[16], xcb, zcb, L_, flagp);
    // xproj (padded N=64, fp32 weights) into xdbl ld 64
    k_gemm_mfma<<<dim3(1, 64), 256, 0, stream>>>(
        xcb, 1, 256, 256, 64, px, nullptr, BIG, 1, nullptr,
        xdbl, nullptr, 64, nullptr, 0,
        nullptr, 1, 0, nullptr, 1, nullptr,
        1.f, 0, 0, flagp);
    // dt (padded K=64, fp32 weights+bias) + fused softplus -> qb, dxc
    k_gemm_mfma<<<dim3(4, 64), 256, 0, stream>>>(
        xdbl, 1, 64, 64, 256, pd, nullptr, BIG, 1, pb,
        qb, nullptr, 256, dxc, 256,
        xcb, 1, 256, nullptr, 1, nullptr,
        1.f, 0, 4, flagp);
    k_scan1<<<1024, 256, 0, stream>>>(qb, dxc, xdbl, in[20], scE, scF, L_, flagp);
    k_scan2<<<32, 256, 0, stream>>>(scE, scF, scH);
    k_scan3<<<1024, 256, 0, stream>>>(qb, dxc, xcb, xdbl, in[20], in[21], scH, kb, L_, flagp);
    // batched s_x / c_x / o-proj (+fused raw-input->cat copy) into cat (ld 1024)
    {
      GB4 gb = {};
      gb.cfl[0] = gb.cfl[1] = gb.cfl[3] = 1;
      gb.A[0] = kb;  gb.W[0] = in[22]; gb.Cf[0] = cat + 512; gb.osc[0] = 1.f;
      gb.A[1] = zcb; gb.W[1] = in[22]; gb.Cf[1] = cat + 768; gb.osc[1] = 1.f;
      gb.A[2] = ob;  gb.W[2] = in[6];  gb.bias[2] = in[7];   gb.Cf[2] = cat + 256;
      gb.csrc[2] = in[i]; gb.cdst[2] = cat; gb.osc[2] = 1.f; gb.cfl[2] = 0;
      k_gemmb<<<dim3(4, 64, 3), 256, 0, stream>>>(gb, 256, 256, 256, 1024, 0, 256, 0, 0, flagp);
    }
    // ffn1 split-K=2: z0 = cat[:,0:512] @ W[:,0:512]^T (+bias), z1 = rest
    {
      GB4 gb = {};
      gb.cfl[0] = gb.cfl[1] = 1;
      gb.A[0] = cat;       gb.W[0] = in[8]; gb.bias[0] = in[9]; gb.Cf[0] = hbuf;  gb.osc[0] = 1.f;
      gb.A[1] = cat + 512; gb.W[1] = in[8]; gb.wkoff[1] = 512;  gb.Cf[1] = partM; gb.osc[1] = 1.f;
      k_gemmb<<<dim3(8, 64, 2), 256, 0, stream>>>(gb, 1024, 512, 512, 512, 0, 1024, 0, 0, flagp);
    }
    k_ln<<<1024, 256, 0, stream>>>(hbuf, partM, in[10], in[11], flagp);
    // ffn2: gelu(A) @ W^T + bias + raw-input residual (dtype-flag-aware)
    k_gemm_mfma<<<dim3(4, 64), 256, 0, stream>>>(
        hbuf, 1, 512, 512, 256, in[12], nullptr, BIG, 0, in[13],
        d, nullptr, 256, nullptr, 0,
        in[i], 0, 256, nullptr, 1, nullptr,
        1.f, 1, 0, flagp);
  }

  // ---------------- cross attention ----------------
  const float s4 = 0.35355339059327373f;  // 64^-0.25
  {
    GB4 gb = {};
    gb.cfl[0] = gb.cfl[1] = gb.cfl[2] = gb.cfl[3] = 1;
    gb.A[0] = dbuf[0]; gb.W[0] = in[23]; gb.bias[0] = in[24]; gb.Cb[0] = (u16*)qb; gb.osc[0] = s4;
    gb.A[1] = dbuf[1]; gb.W[1] = in[23]; gb.bias[1] = in[24]; gb.Cb[1] = (u16*)kb; gb.osc[1] = s4;
    gb.A[2] = dbuf[0]; gb.W[2] = in[25]; gb.bias[2] = in[26]; gb.Cb[2] = (u16*)vb; gb.osc[2] = 1.f;
    gb.A[3] = dbuf[1]; gb.W[3] = in[25]; gb.bias[3] = in[26]; gb.Cb[3] = (u16*)ob; gb.osc[3] = 1.f;
    k_gemmb<<<dim3(4, 64, 4), 256, 0, stream>>>(gb, 256, 256, 256, 256, 0, 256, 0, 3, flagp);
  }
  k_attn_mfma<<<gAttn, 256, 0, stream>>>((u16*)qb, sbF, shF, slF, (u16*)kb, sbF, shF, slF,
                                         (u16*)ob, sbF, shF, slF,
                                         cat, mml, mll, L_, H_, kchunk);
  k_attn_comb<<<(int)(BLE/256), 256, 0, stream>>>(cat, mml, mll, xcb, BHL);
  k_attn_mfma<<<gAttn, 256, 0, stream>>>((u16*)kb, sbF, shF, slF, (u16*)qb, sbF, shF, slF,
                                         (u16*)vb, sbF, shF, slF,
                                         cat, mml, mll, L_, H_, kchunk);
  k_attn_comb<<<(int)(BLE/256), 256, 0, stream>>>(cat, mml, mll, zcb, BHL);
  {
    GB4 gb = {};
    gb.cfl[0] = gb.cfl[1] = 1;
    gb.A[0] = xcb; gb.W[0] = in[27]; gb.bias[0] = in[28]; gb.Cf[0] = catA + 256;
    gb.csrc[0] = dbuf[0]; gb.cdst[0] = catA; gb.osc[0] = 1.f;
    gb.A[1] = zcb; gb.W[1] = in[27]; gb.bias[1] = in[28]; gb.Cf[1] = catB + 256;
    gb.csrc[1] = dbuf[1]; gb.cdst[1] = catB; gb.osc[1] = 1.f;
    k_gemmb<<<dim3(4, 64, 2), 256, 0, stream>>>(gb, 256, 256, 256, 512, 0, 256, 0, 0, flagp);
  }
  // ca-ffn1 split-K=2 per descriptor (z=4 total); bias on z0/z2 only
  {
    GB4 gb = {};
    gb.cfl[0] = gb.cfl[1] = gb.cfl[2] = gb.cfl[3] = 1;
    gb.A[0] = catA;       gb.W[0] = in[29]; gb.bias[0] = in[30]; gb.Cf[0] = hbuf;  gb.osc[0] = 1.f;
    gb.A[1] = catA + 256; gb.W[1] = in[29]; gb.wkoff[1] = 256;   gb.Cf[1] = partM; gb.osc[1] = 1.f;
    gb.A[2] = catB;       gb.W[2] = in[29]; gb.bias[2] = in[30]; gb.Cf[2] = hbufB; gb.osc[2] = 1.f;
    gb.A[3] = catB + 256; gb.W[3] = in[29]; gb.wkoff[3] = 256;   gb.Cf[3] = partB; gb.osc[3] = 1.f;
    k_gemmb<<<dim3(8, 64, 4), 256, 0, stream>>>(gb, 512, 256, 512, 512, 0, 512, 0, 0, flagp);
  }
  k_ln2<<<2048, 256, 0, stream>>>(hbuf, partM, hbufB, partB, in[31], in[32], flagp);
  {
    GB4 gb = {};
    gb.cfl[0] = gb.cfl[1] = 1;
    gb.A[0] = hbuf;  gb.W[0] = in[33]; gb.bias[0] = in[34]; gb.resid[0] = dbuf[0];
    gb.Cf[0] = (float*)d_out; gb.Cb[0] = (u16*)d_out; gb.osc[0] = 1.f;
    gb.A[1] = hbufB; gb.W[1] = in[33]; gb.bias[1] = in[34]; gb.resid[1] = dbuf[1];
    gb.Cf[1] = (float*)d_out + BLE; gb.Cb[1] = (u16*)d_out + BLE; gb.osc[1] = 1.f;
    k_gemmb<<<dim3(4, 64, 2), 256, 0, stream>>>(gb, 512, 512, 256, 256, 256, 512, 1, 2, flagp);
  }
}